// Round 11
// baseline (67.319 us; speedup 1.0000x reference)
//
#include <hip/hip_runtime.h>

#define N_TASKS 16
#define LMAX 64
#define TSTRIDE 136
#define BLOCK 256
#define ITERS 32
#define ROWS_PER_BLOCK 512   // 32 chunks x 16 consecutive rows

typedef float f32x4 __attribute__((ext_vector_type(4)));
typedef float f32x2 __attribute__((ext_vector_type(2)));

// Hot kernel (requires total4 == gridDim.x * BLOCK * ITERS):
// R8 structure + all row gathers hoisted to a prologue burst into LDS.
// Row ds_read_b64 is software-pipelined one iteration ahead (R5's trick,
// applied to LDS) so the steady-state loop keeps single-hop LDS depth:
// {b64 for it+1, 2x b128 for it (deps ready), 4 FMA, nt store}, no VMEM loads.
__global__ __launch_bounds__(BLOCK) void MEWA_exact_kernel(
    const float* __restrict__ input,      // [B]
    const int*   __restrict__ task_ids,   // [B]
    const float* __restrict__ offsets,    // [N_TASKS*LMAX]
    const float* __restrict__ disc,       // [N_TASKS*LMAX]
    const int*   __restrict__ lengths,    // [N_TASKS]
    f32x4*       __restrict__ out)        // [B*16]
{
    __shared__ alignas(16) float s_tab[N_TASKS * TSTRIDE];     // [t]: m / m*o
    __shared__ alignas(8)  f32x2 s_row[ROWS_PER_BLOCK + 16];   // +16 = pipeline pad

    const int tid          = threadIdx.x;
    const int chunk_stride = gridDim.x * 16;   // rows between iterations
    const int row0         = blockIdx.x * 16;

    for (int i = tid; i < N_TASKS * LMAX; i += BLOCK) {
        int t = i >> 6, k = i & (LMAX - 1);
        float m = (k < lengths[t]) ? disc[i] : 0.0f;
        s_tab[t * TSTRIDE + k]      = m;
        s_tab[t * TSTRIDE + 64 + k] = m * offsets[i];
    }
    // Prologue read burst: stage this block's 512 rows ({x, task}) into LDS.
    for (int i = tid; i < ROWS_PER_BLOCK + 16; i += BLOCK) {
        f32x2 v; v.x = 0.0f; v.y = __int_as_float(0);
        if (i < ROWS_PER_BLOCK) {
            int r = row0 + (i & 15) + (i >> 4) * chunk_stride;
            v.x = input[r];
            v.y = __int_as_float(task_ids[r]);
        }
        s_row[i] = v;
    }
    __syncthreads();

    const int  k4     = tid & 15;
    const int  lg     = tid >> 4;              // row within chunk
    const long stride = (long)gridDim.x * BLOCK;
    const long gbase  = (long)blockIdx.x * BLOCK + tid;

    f32x2 rv_cur = s_row[lg];                  // prime pipeline (iteration 0)

    for (int it = 0; it < ITERS; ++it) {
        f32x2 rv_nxt = s_row[(it + 1) * 16 + lg];   // ds_read_b64 for it+1, no dep
        float x  = rv_cur.x;
        int   t  = __float_as_int(rv_cur.y);
        const float* base = &s_tab[t * TSTRIDE + (k4 << 2)];
        f32x4 mv = *(const f32x4*)(base);           // ds_read_b128 (dep ready)
        f32x4 pv = *(const f32x4*)(base + 64);      // ds_read_b128 offset:256
        f32x4 r;
        r.x = fmaf(mv.x, x, pv.x);
        r.y = fmaf(mv.y, x, pv.y);
        r.z = fmaf(mv.z, x, pv.z);
        r.w = fmaf(mv.w, x, pv.w);
        __builtin_nontemporal_store(r, &out[gbase + it * stride]);  // dense 1KB/wave
        rv_cur = rv_nxt;
    }
}

// Fallback (any size): R8 champion kernel verbatim (in-loop gathers, nt).
__global__ __launch_bounds__(BLOCK) void MEWA_generic_kernel(
    const float* __restrict__ input, const int* __restrict__ task_ids,
    const float* __restrict__ offsets, const float* __restrict__ disc,
    const int* __restrict__ lengths, f32x4* __restrict__ out, int total4)
{
    __shared__ alignas(16) float s_tab[N_TASKS * TSTRIDE];
    for (int i = threadIdx.x; i < N_TASKS * LMAX; i += BLOCK) {
        int t = i >> 6, k = i & (LMAX - 1);
        float m = (k < lengths[t]) ? disc[i] : 0.0f;
        s_tab[t * TSTRIDE + k]      = m;
        s_tab[t * TSTRIDE + 64 + k] = m * offsets[i];
    }
    __syncthreads();
    const int stride = gridDim.x * blockDim.x;
    int g = blockIdx.x * blockDim.x + threadIdx.x;
    if (g >= total4) return;
    int   t_cur = task_ids[g >> 4];
    float x_cur = input[g >> 4];
    for (; g < total4; g += stride) {
        int gn = g + stride;
        int rown = (gn < total4 ? gn : g) >> 4;
        int t_nxt = task_ids[rown];
        float x_nxt = input[rown];
        int k4 = g & 15;
        const float* base = &s_tab[t_cur * TSTRIDE + (k4 << 2)];
        f32x4 mv = *(const f32x4*)(base);
        f32x4 pv = *(const f32x4*)(base + 64);
        f32x4 r;
        r.x = fmaf(mv.x, x_cur, pv.x);
        r.y = fmaf(mv.y, x_cur, pv.y);
        r.z = fmaf(mv.z, x_cur, pv.z);
        r.w = fmaf(mv.w, x_cur, pv.w);
        __builtin_nontemporal_store(r, &out[g]);
        t_cur = t_nxt;
        x_cur = x_nxt;
    }
}

extern "C" void kernel_launch(void* const* d_in, const int* in_sizes, int n_in,
                              void* d_out, int out_size, void* d_ws, size_t ws_size,
                              hipStream_t stream) {
    const float* input    = (const float*)d_in[0];
    const int*   task_ids = (const int*)d_in[1];
    const float* offsets  = (const float*)d_in[2];
    const float* disc     = (const float*)d_in[3];
    const int*   lengths  = (const int*)d_in[4];
    f32x4*       out      = (f32x4*)d_out;

    int total4 = out_size / 4;                 // B * 16
    int grid   = total4 / (BLOCK * ITERS);     // 2048 for B=1M

    if (grid >= 1 && grid * BLOCK * ITERS == total4) {
        MEWA_exact_kernel<<<grid, BLOCK, 0, stream>>>(
            input, task_ids, offsets, disc, lengths, out);
    } else {
        int g2 = (total4 + BLOCK - 1) / BLOCK;
        if (g2 > 2048) g2 = 2048;
        MEWA_generic_kernel<<<g2, BLOCK, 0, stream>>>(
            input, task_ids, offsets, disc, lengths, out, total4);
    }
}

// Round 12
// 48.558 us; speedup vs baseline: 1.3863x; 1.3863x over previous
//
#include <hip/hip_runtime.h>

#define N_TASKS 16
#define LMAX 64
#define TSTRIDE 136  // dwords per task row (A/B-neutral vs 128; kept from R8)

typedef float f32x4 __attribute__((ext_vector_type(4)));

__global__ __launch_bounds__(256) void MultiElementWiseAffine_kernel(
    const float* __restrict__ input,      // [B]
    const int*   __restrict__ task_ids,   // [B]
    const float* __restrict__ offsets,    // [N_TASKS*LMAX]
    const float* __restrict__ disc,       // [N_TASKS*LMAX]
    const int*   __restrict__ lengths,    // [N_TASKS]
    f32x4*       __restrict__ out,        // [B*16] float4 view of [B][64]
    int total4)                           // B*16
{
    // Per-task: [t*136 + 0..63] = masked disc (m), [t*136 + 64..127] = m*offset.
    __shared__ alignas(16) float s_tab[N_TASKS * TSTRIDE];

    for (int i = threadIdx.x; i < N_TASKS * LMAX; i += blockDim.x) {
        int t = i >> 6;          // task
        int k = i & (LMAX - 1);  // threshold index
        float m = (k < lengths[t]) ? disc[i] : 0.0f;
        s_tab[t * TSTRIDE + k]      = m;
        s_tab[t * TSTRIDE + 64 + k] = m * offsets[i];
    }
    __syncthreads();

    const int stride = gridDim.x * blockDim.x;
    int g = blockIdx.x * blockDim.x + threadIdx.x;
    if (g >= total4) return;

    // 2-stage pipeline: next iteration's row data prefetched -> table ds_reads
    // issue at loop top (single LDS hop per iteration). In-loop gathers are
    // PROVEN faster than LDS row-staging (R7/R9/R11 all ~ +15us).
    int   t_cur = task_ids[g >> 4];
    float x_cur = input[g >> 4];

    for (; g < total4; g += stride) {
        int gn      = g + stride;
        int rown    = (gn < total4 ? gn : g) >> 4;
        int t_nxt   = task_ids[rown];
        float x_nxt = input[rown];

        int k4 = g & 15;
        const float* base = &s_tab[t_cur * TSTRIDE + (k4 << 2)];
        f32x4 mv = *(const f32x4*)(base);       // ds_read_b128
        f32x4 pv = *(const f32x4*)(base + 64);  // ds_read_b128 offset:256
        f32x4 r;
        r.x = fmaf(mv.x, x_cur, pv.x);
        r.y = fmaf(mv.y, x_cur, pv.y);
        r.z = fmaf(mv.z, x_cur, pv.z);
        r.w = fmaf(mv.w, x_cur, pv.w);
        // Lane-dense 1KB/wave, grid-stride walk, nt (all three A/B-proven).
        __builtin_nontemporal_store(r, &out[g]);

        t_cur = t_nxt;
        x_cur = x_nxt;
    }
}

extern "C" void kernel_launch(void* const* d_in, const int* in_sizes, int n_in,
                              void* d_out, int out_size, void* d_ws, size_t ws_size,
                              hipStream_t stream) {
    const float* input    = (const float*)d_in[0];
    const int*   task_ids = (const int*)d_in[1];
    const float* offsets  = (const float*)d_in[2];
    const float* disc     = (const float*)d_in[3];
    const int*   lengths  = (const int*)d_in[4];
    f32x4*       out      = (f32x4*)d_out;

    int total4 = out_size / 4;           // B * 16
    int block  = 256;
    // ONLY change vs R8: grid 2048 -> 512 (2 blocks/CU, 8 waves/CU).
    // Mirrors the 7 TB/s fill kernel's low-concurrency recipe (~10% occupancy)
    // while keeping enough waves to hide the in-loop gather/LDS latency.
    int grid   = 512;

    MultiElementWiseAffine_kernel<<<grid, block, 0, stream>>>(
        input, task_ids, offsets, disc, lengths, out, total4);
}